// Round 12
// baseline (180.948 us; speedup 1.0000x reference)
//
#include <hip/hip_runtime.h>

#define BB 8
#define CC 512
#define LL 2048
#define GG 4
#define CPG 128   // channels per group

typedef _Float16 f16;
typedef _Float16 f16x4 __attribute__((ext_vector_type(4)));
typedef _Float16 f16x8 __attribute__((ext_vector_type(8)));
typedef float f32x4 __attribute__((ext_vector_type(4)));

__device__ __forceinline__ void gload_lds16(const f16* g, f16* l)
{
    __builtin_amdgcn_global_load_lds(
        (__attribute__((address_space(1))) void*)g,
        (__attribute__((address_space(3))) void*)l, 16, 0, 0);
}

// ---------------------------------------------------------------------------
// Fused: weight conversion, vectorized float4->f16x4 (blocks 0-255)
//        + GroupNorm partial sums (blocks 256-1279)
// ---------------------------------------------------------------------------
__global__ __launch_bounds__(256) void convert_gn(
    const float* __restrict__ qw, const float* __restrict__ kw,
    const float* __restrict__ vw, const float* __restrict__ pw,
    const float* __restrict__ qb, const float* __restrict__ kb,
    const float* __restrict__ x,
    f16* __restrict__ Wqk, f16* __restrict__ Wv, f16* __restrict__ Wp,
    float* __restrict__ qkb, float2* __restrict__ part)
{
    int bid = blockIdx.x;
    if (bid < 256) {
        int j = bid * 256 + threadIdx.x;
        int i = j * 4;
        float4 q4 = *(const float4*)(qw + i);
        float4 k4 = *(const float4*)(kw + i);
        float4 v4 = *(const float4*)(vw + i);
        float4 p4 = *(const float4*)(pw + i);
        f16x4 o;
        o[0] = (f16)q4.x; o[1] = (f16)q4.y; o[2] = (f16)q4.z; o[3] = (f16)q4.w;
        *(f16x4*)(Wqk + i) = o;
        o[0] = (f16)k4.x; o[1] = (f16)k4.y; o[2] = (f16)k4.z; o[3] = (f16)k4.w;
        *(f16x4*)(Wqk + CC * CC + i) = o;
        o[0] = (f16)v4.x; o[1] = (f16)v4.y; o[2] = (f16)v4.z; o[3] = (f16)v4.w;
        *(f16x4*)(Wv + i) = o;
        o[0] = (f16)p4.x; o[1] = (f16)p4.y; o[2] = (f16)p4.z; o[3] = (f16)p4.w;
        *(f16x4*)(Wp + i) = o;
        if (j < CC) { qkb[j] = qb[j]; qkb[CC + j] = kb[j]; }
    } else {
        int r = bid - 256;
        int s = r & 31, g = (r >> 5) & 3, b = r >> 7;
        const float4* p = (const float4*)(x + (size_t)b * CC * LL
                                            + (size_t)g * CPG * LL + (size_t)s * 8192);
        float sum = 0.f, sq = 0.f;
        for (int i = threadIdx.x; i < 2048; i += 256) {
            float4 v = p[i];
            sum += v.x + v.y + v.z + v.w;
            sq  += v.x * v.x + v.y * v.y + v.z * v.z + v.w * v.w;
        }
        for (int o = 32; o; o >>= 1) { sum += __shfl_xor(sum, o); sq += __shfl_xor(sq, o); }
        __shared__ float2 red[4];
        int wave = threadIdx.x >> 6, lane = threadIdx.x & 63;
        if (lane == 0) red[wave] = make_float2(sum, sq);
        __syncthreads();
        if (threadIdx.x == 0) {
            float S = red[0].x + red[1].x + red[2].x + red[3].x;
            float Q = red[0].y + red[1].y + red[2].y + red[3].y;
            part[((size_t)b * GG + g) * 32 + s] = make_float2(S, Q);
        }
    }
}

// GroupNorm normalize + affine + TRANSPOSE: x [C,L] fp32 -> xnT [L,C] f16.
__global__ __launch_bounds__(256) void gn_norm_t(
    const float* __restrict__ x, const float2* __restrict__ part,
    const float* __restrict__ gw, const float* __restrict__ gb,
    f16* __restrict__ xnT)
{
    __shared__ float t[64][65];
    __shared__ float2 stLds;
    int l0 = blockIdx.x * 64, c0 = blockIdx.y * 64, b = blockIdx.z;
    int tid = threadIdx.x;
    if (tid < 32) {
        float2 p = part[((size_t)b * GG + (c0 >> 7)) * 32 + tid];
        float s = p.x, q = p.y;
        for (int o = 16; o; o >>= 1) { s += __shfl_xor(s, o); q += __shfl_xor(q, o); }
        if (tid == 0) {
            const float invN = 1.0f / (float)(CPG * LL);
            float mean = s * invN;
            float var  = q * invN - mean * mean;
            stLds = make_float2(mean, rsqrtf(var + 1e-6f));
        }
    }
    __syncthreads();
    float2 st = stLds;
    const float* xb = x + (size_t)b * CC * LL;
    {
        int c = tid >> 2, lb = (tid & 3) * 16;
        float g = gw[c0 + c], b2 = gb[c0 + c];
        const float4* src = (const float4*)(xb + (size_t)(c0 + c) * LL + l0 + lb);
#pragma unroll
        for (int q = 0; q < 4; ++q) {
            float4 v = src[q];
            int l = lb + q * 4;
            t[c][l + 0] = (v.x - st.x) * st.y * g + b2;
            t[c][l + 1] = (v.y - st.x) * st.y * g + b2;
            t[c][l + 2] = (v.z - st.x) * st.y * g + b2;
            t[c][l + 3] = (v.w - st.x) * st.y * g + b2;
        }
    }
    __syncthreads();
    f16* o = xnT + (size_t)b * LL * CC;
    {
        int c8 = (tid & 7) * 8;
#pragma unroll
        for (int h = 0; h < 2; ++h) {
            int l = (tid >> 3) + h * 32;
            f16x8 v;
#pragma unroll
            for (int u = 0; u < 8; ++u) v[u] = (f16)t[c8 + u][l];
            *(f16x8*)(o + (size_t)(l0 + l) * CC + c0 + c8) = v;
        }
    }
}

// ---------------------------------------------------------------------------
// Pipelined GEMM (counted-vmcnt, never drains):  C = alpha*A[M,K]·B[N,K]^T
// Tile 128x256, BK=64, 512 threads = 8 waves (2M x 4N), per-wave 64x64.
// LDS: 2 dbuf x (A 16KB + B 32KB) = 96 KB -> 1 block/CU (intra-block pipe).
// Per K-tile, 3 phases; staging of tile t+1 split into 6 per-wave loads
// issued ph1:3, ph2:2, ph3:1.  Per-wave load queue (oldest first) at each
// check (derived invariant, steady state, st = more tiles to stage):
//   after ph1 MFMA: [ph2set(t)=2, ph3set(t)=1, ph1set(t+1)=3] -> vmcnt(4)
//                    confirms ph2set(t) (B second-halves, read in ph2)
//   after ph2 MFMA: [ph3set(t)=1, ph1set(t+1)=3, ph2set(t+1)=2] -> vmcnt(5)
//                    confirms ph3set(t) (A second-halves, read in ph3)
//   after ph3 MFMA: [ph1set(t+1)=3, ph2set(t+1)=2, ph3set(t+1)=1] -> vmcnt(3)
//                    confirms ph1set(t+1) before next tile's ph1 reads
// Last tile (no staging): vmcnt(1)/(0)/(0).  Every check precedes a
// s_barrier, making all waves' contributions visible (R2-proven mechanism).
// dbuf safety: stage(t+1) writes dbuf[(t+1)&1], last read in tile t-1,
// separated by t-1's closing barrier.
// Swizzle: phys=(row*128+col)^((row&7)<<4) (R2-verified 0-conflict);
// gload_lds linear dest + inverse-swizzled source col ((l&7)^(l>>3))*8.
// ---------------------------------------------------------------------------
template<int BIAS_MODE, bool SOFTEXP, bool ROWSCALE, typename OUT_T>
__global__ __launch_bounds__(512, 2) void gemm_pipe(
    const f16* __restrict__ A, size_t sA,
    const f16* __restrict__ B, size_t sB,
    OUT_T* __restrict__ Co, size_t sC,
    const float* __restrict__ bias, float* __restrict__ rowpart,
    int M, int K, int lda, int ldb, int ldc, float alpha)
{
    const int tid = threadIdx.x, lane = tid & 63, w = tid >> 6;
    const int l15 = lane & 15, lhi = lane >> 4;
    const int wr = w >> 2, wc = w & 3;

    // XCD-aware bijective swizzle over flattened grid (nwg % 8 == 0)
    const int GX = gridDim.x, GXY = gridDim.x * gridDim.y;
    const int nwg = GXY * gridDim.z;
    int lin = blockIdx.z * GXY + blockIdx.y * GX + blockIdx.x;
    int logical = (lin & 7) * (nwg >> 3) + (lin >> 3);
    const int bz = logical / GXY;
    int rem = logical - bz * GXY;
    const int bm = rem / GX;
    const int bn = rem - bm * GX;

    A  += (size_t)bz * sA + (size_t)(bm * 128) * lda;
    B  += (size_t)bz * sB + (size_t)(bn * 256) * ldb;
    Co += (size_t)bz * sC;

    __shared__ f16 ldsA[2][128 * 64];
    __shared__ f16 ldsB[2][256 * 64];
    __shared__ float rs[4][128];
    __shared__ float rsl[128];

    f32x4 acc[4][4] = {};

    if constexpr (ROWSCALE) {
        if (tid < 128) {
            const float* rp = rowpart + ((size_t)bz * M + bm * 128 + tid) * 8;
            float s = 0.f;
#pragma unroll
            for (int k = 0; k < 8; ++k) s += rp[k];
            rsl[tid] = 1.0f / s;
        }
        // ordered before epilogue use by the loop's barriers
    }

    // staging geometry: each load = 8KB unit-pair, wave w covers 8 rows
    const int srcColE = ((lane & 7) ^ (lane >> 3)) * 8;   // inverse swizzle
    const int sub = (w & 3) * 8 + (lane >> 3);            // 0..31 row-in-32
    const int half = w >> 2;                              // 0/1
    const int ldst = half * 8192 + (w & 3) * 1024;        // LDS wave chunk

    // per-tile stage sets (issue order is the correctness invariant!)
    auto S_A1 = [&](int t) {   // A rows half*64 + [0,32)
        gload_lds16(A + (size_t)(half * 64 + sub) * lda + t * 64 + srcColE,
                    (f16*)((char*)ldsA[t & 1] + ldst)); };
    auto S_B1 = [&](int t) {   // B rows half*64 + [0,32)  (quarters 0,1)
        gload_lds16(B + (size_t)(half * 64 + sub) * ldb + t * 64 + srcColE,
                    (f16*)((char*)ldsB[t & 1] + ldst)); };
    auto S_B2 = [&](int t) {   // B rows 128 + half*64 + [0,32) (quarters 2,3)
        gload_lds16(B + (size_t)(128 + half * 64 + sub) * ldb + t * 64 + srcColE,
                    (f16*)((char*)ldsB[t & 1] + 16384 + ldst)); };
    auto S_B1b = [&](int t) {  // B rows half*64 + [32,64)
        gload_lds16(B + (size_t)(half * 64 + 32 + sub) * ldb + t * 64 + srcColE,
                    (f16*)((char*)ldsB[t & 1] + 4096 + ldst)); };
    auto S_B2b = [&](int t) {  // B rows 128 + half*64 + [32,64)
        gload_lds16(B + (size_t)(128 + half * 64 + 32 + sub) * ldb + t * 64 + srcColE,
                    (f16*)((char*)ldsB[t & 1] + 20480 + ldst)); };
    auto S_A1b = [&](int t) {  // A rows half*64 + [32,64)
        gload_lds16(A + (size_t)(half * 64 + 32 + sub) * lda + t * 64 + srcColE,
                    (f16*)((char*)ldsA[t & 1] + 4096 + ldst)); };

    auto rd = [&](const f16* tile, int row, int byteCol) -> f16x8 {
        return *(const f16x8*)((const char*)tile
            + (((row << 7) + byteCol) ^ ((row & 7) << 4)));
    };

    const int NT = K >> 6;

    // prologue: tile 0 in canonical order, confirm ph1set(0), leave 3
    S_A1(0); S_B1(0); S_B2(0); S_B1b(0); S_B2b(0); S_A1b(0);
    asm volatile("s_waitcnt vmcnt(3)" ::: "memory");
    __builtin_amdgcn_s_barrier();

    for (int t = 0; t < NT; ++t) {
        const f16* cA = ldsA[t & 1];
        const f16* cB = ldsB[t & 1];
        const bool st = (t < NT - 1);
        f16x8 a01[2][2], a23[2][2], b01[2][2], b23[2][2];
        // ---- phase 1: m01 x n01
#pragma unroll
        for (int m = 0; m < 2; ++m)
#pragma unroll
            for (int kk = 0; kk < 2; ++kk)
                a01[m][kk] = rd(cA, wr * 64 + m * 16 + l15, kk * 64 + lhi * 16);
#pragma unroll
        for (int n = 0; n < 2; ++n)
#pragma unroll
            for (int kk = 0; kk < 2; ++kk)
                b01[n][kk] = rd(cB, wc * 64 + n * 16 + l15, kk * 64 + lhi * 16);
        if (st) { S_A1(t + 1); S_B1(t + 1); S_B2(t + 1); }
        asm volatile("s_waitcnt lgkmcnt(0)" ::: "memory");
        __builtin_amdgcn_sched_barrier(0);
        __builtin_amdgcn_s_setprio(1);
#pragma unroll
        for (int m = 0; m < 2; ++m)
#pragma unroll
            for (int n = 0; n < 2; ++n)
#pragma unroll
                for (int kk = 0; kk < 2; ++kk)
                    acc[m][n] = __builtin_amdgcn_mfma_f32_16x16x32_f16(
                        a01[m][kk], b01[n][kk], acc[m][n], 0, 0, 0);
        __builtin_amdgcn_s_setprio(0);
        if (st) asm volatile("s_waitcnt vmcnt(4)" ::: "memory");
        else    asm volatile("s_waitcnt vmcnt(1)" ::: "memory");
        __builtin_amdgcn_s_barrier();
        // ---- phase 2: m01 x n23
#pragma unroll
        for (int n = 0; n < 2; ++n)
#pragma unroll
            for (int kk = 0; kk < 2; ++kk)
                b23[n][kk] = rd(cB, wc * 64 + 32 + n * 16 + l15, kk * 64 + lhi * 16);
        if (st) { S_B1b(t + 1); S_B2b(t + 1); }
        asm volatile("s_waitcnt lgkmcnt(0)" ::: "memory");
        __builtin_amdgcn_sched_barrier(0);
        __builtin_amdgcn_s_setprio(1);
#pragma unroll
        for (int m = 0; m < 2; ++m)
#pragma unroll
            for (int n = 0; n < 2; ++n)
#pragma unroll
                for (int kk = 0; kk < 2; ++kk)
                    acc[m][n + 2] = __builtin_amdgcn_mfma_f32_16x16x32_f16(
                        a01[m][kk], b23[n][kk], acc[m][n + 2], 0, 0, 0);
        __builtin_amdgcn_s_setprio(0);
        if (st) asm volatile("s_waitcnt vmcnt(5)" ::: "memory");
        else    asm volatile("s_waitcnt vmcnt(0)" ::: "memory");
        __builtin_amdgcn_s_barrier();
        // ---- phase 3: m23 x n0123
#pragma unroll
        for (int m = 0; m < 2; ++m)
#pragma unroll
            for (int kk = 0; kk < 2; ++kk)
                a23[m][kk] = rd(cA, wr * 64 + 32 + m * 16 + l15, kk * 64 + lhi * 16);
        if (st) { S_A1b(t + 1); }
        asm volatile("s_waitcnt lgkmcnt(0)" ::: "memory");
        __builtin_amdgcn_sched_barrier(0);
        __builtin_amdgcn_s_setprio(1);
#pragma unroll
        for (int m = 0; m < 2; ++m)
#pragma unroll
            for (int n = 0; n < 2; ++n)
#pragma unroll
                for (int kk = 0; kk < 2; ++kk) {
                    acc[m + 2][n] = __builtin_amdgcn_mfma_f32_16x16x32_f16(
                        a23[m][kk], b01[n][kk], acc[m + 2][n], 0, 0, 0);
                    acc[m + 2][n + 2] = __builtin_amdgcn_mfma_f32_16x16x32_f16(
                        a23[m][kk], b23[n][kk], acc[m + 2][n + 2], 0, 0, 0);
                }
        __builtin_amdgcn_s_setprio(0);
        if (st) asm volatile("s_waitcnt vmcnt(3)" ::: "memory");
        __builtin_amdgcn_s_barrier();
    }

    // ---- epilogue (per-wave 64 rows x 64 cols at (wr*64, wc*64))
    if constexpr (SOFTEXP) {
        float rowacc[16];
#pragma unroll
        for (int i = 0; i < 16; ++i) rowacc[i] = 0.f;
#pragma unroll
        for (int m = 0; m < 4; ++m) {
#pragma unroll
            for (int n = 0; n < 4; ++n) {
                int col = bn * 256 + wc * 64 + n * 16 + l15;
#pragma unroll
                for (int r = 0; r < 4; ++r) {
                    int row = bm * 128 + wr * 64 + m * 16 + lhi * 4 + r;
                    float e = __expf(fminf(acc[m][n][r] * alpha, 11.0f));
                    rowacc[m * 4 + r] += e;
                    Co[(size_t)row * ldc + col] = (OUT_T)e;
                }
            }
        }
#pragma unroll
        for (int off = 1; off < 16; off <<= 1)
#pragma unroll
            for (int i = 0; i < 16; ++i)
                rowacc[i] += __shfl_xor(rowacc[i], off);
        if (l15 == 0) {
#pragma unroll
            for (int i = 0; i < 16; ++i)
                rs[wc][wr * 64 + (i >> 2) * 16 + lhi * 4 + (i & 3)] = rowacc[i];
        }
        __syncthreads();
        if (tid < 128) {
            int row = bm * 128 + tid;
            rowpart[((size_t)bz * M + row) * gridDim.x + bn] =
                rs[0][tid] + rs[1][tid] + rs[2][tid] + rs[3][tid];
        }
    } else {
#pragma unroll
        for (int m = 0; m < 4; ++m) {
#pragma unroll
            for (int n = 0; n < 4; ++n) {
                int col = bn * 256 + wc * 64 + n * 16 + l15;
#pragma unroll
                for (int r = 0; r < 4; ++r) {
                    int row = bm * 128 + wr * 64 + m * 16 + lhi * 4 + r;
                    float v = acc[m][n][r] * alpha;
                    if (BIAS_MODE == 2) v += bias[col];
                    if (ROWSCALE) v *= rsl[row - bm * 128];
                    Co[(size_t)row * ldc + col] = (OUT_T)v;
                }
            }
        }
    }
}

// ---------------------------------------------------------------------------
// Proven R2-core GEMM (for GEMM2 / GEMM5): tile 128x128, 4 waves, 2-barrier.
// ---------------------------------------------------------------------------
template<int BIAS_MODE, bool RESID, typename OUT_T>
__global__ __launch_bounds__(256, 2) void gemm_bt(
    const f16* __restrict__ A, size_t sA,
    const f16* __restrict__ B, size_t sB,
    OUT_T* __restrict__ Co, size_t sC,
    const float* __restrict__ resid, size_t sR,
    const float* __restrict__ bias,
    int M, int N, int K, int lda, int ldb, int ldc, float alpha)
{
    const int tid  = threadIdx.x;
    const int lane = tid & 63;
    const int wave = tid >> 6;
    const int wr = wave >> 1, wc = wave & 1;
    const int l15 = lane & 15, lhi = lane >> 4;

    const int GX = gridDim.x, GXY = gridDim.x * gridDim.y;
    const int nwg = GXY * gridDim.z;
    int lin = blockIdx.z * GXY + blockIdx.y * GX + blockIdx.x;
    int logical = (lin & 7) * (nwg >> 3) + (lin >> 3);
    const int bz = logical / GXY;
    int rem = logical - bz * GXY;
    const int bm = rem / GX;
    const int bn = rem - bm * GX;

    A  += (size_t)bz * sA;
    B  += (size_t)bz * sB;
    Co += (size_t)bz * sC;

    __shared__ f16 ldsA[128 * 64];
    __shared__ f16 ldsB[128 * 64];

    f32x4 acc[4][4] = {};

    const int srcColE = ((lane & 7) ^ (lane >> 3)) * 8;
    const int rowBase = wave * 8 + (lane >> 3);
    const f16* Ag = A + (size_t)(bm * 128 + rowBase) * lda + srcColE;
    const f16* Bg = B + (size_t)(bn * 128 + rowBase) * ldb + srcColE;

    for (int k0 = 0; k0 < K; k0 += 64) {
#pragma unroll
        for (int it = 0; it < 4; ++it) {
            gload_lds16(Ag + (size_t)(it * 32) * lda + k0,
                        (f16*)((char*)ldsA + it * 4096 + wave * 1024));
            gload_lds16(Bg + (size_t)(it * 32) * ldb + k0,
                        (f16*)((char*)ldsB + it * 4096 + wave * 1024));
        }
        __syncthreads();
#pragma unroll
        for (int kk = 0; kk < 64; kk += 32) {
            const int kb2 = (kk + lhi * 8) * 2;
            f16x8 af[4], bfr[4];
#pragma unroll
            for (int m = 0; m < 4; ++m) {
                int row = wr * 64 + m * 16 + l15;
                int phys = ((row * 128 + kb2) ^ ((row & 7) << 4)) >> 1;
                af[m] = *(const f16x8*)(ldsA + phys);
            }
#pragma unroll
            for (int n = 0; n < 4; ++n) {
                int row = wc * 64 + n * 16 + l15;
                int phys = ((row * 128 + kb2) ^ ((row & 7) << 4)) >> 1;
                bfr[n] = *(const f16x8*)(ldsB + phys);
            }
#pragma unroll
            for (int m = 0; m < 4; ++m)
#pragma unroll
                for (int n = 0; n < 4; ++n)
                    acc[m][n] = __builtin_amdgcn_mfma_f32_16x16x32_f16(
                        af[m], bfr[n], acc[m][n], 0, 0, 0);
        }
        __syncthreads();
    }

#pragma unroll
    for (int m = 0; m < 4; ++m) {
#pragma unroll
        for (int n = 0; n < 4; ++n) {
            int col = bn * 128 + wc * 64 + n * 16 + l15;
#pragma unroll
            for (int r = 0; r < 4; ++r) {
                int row = bm * 128 + wr * 64 + m * 16 + lhi * 4 + r;
                float v = acc[m][n][r] * alpha;
                if (BIAS_MODE == 1) v += bias[row];
                if (BIAS_MODE == 2) v += bias[col];
                if (RESID) v += resid[(size_t)bz * sR + (size_t)row * ldc + col];
                Co[(size_t)row * ldc + col] = (OUT_T)v;
            }
        }
    }
}

// Fallback marker if workspace is too small
__global__ void fill_marker(float* out, int n)
{
    int i = blockIdx.x * 256 + threadIdx.x;
    if (i < n) out[i] = 12345.0f;
}

// ---------------------------------------------------------------------------
extern "C" void kernel_launch(void* const* d_in, const int* in_sizes, int n_in,
                              void* d_out, int out_size, void* d_ws, size_t ws_size,
                              hipStream_t stream)
{
    const float* x  = (const float*)d_in[0];
    const float* gw = (const float*)d_in[1];
    const float* gb = (const float*)d_in[2];
    const float* qw = (const float*)d_in[3];
    const float* qb = (const float*)d_in[4];
    const float* kw = (const float*)d_in[5];
    const float* kb = (const float*)d_in[6];
    const float* vw = (const float*)d_in[7];
    const float* vb = (const float*)d_in[8];
    const float* pw = (const float*)d_in[9];
    const float* pb = (const float*)d_in[10];
    float* out = (float*)d_out;

    char* w = (char*)d_ws;
    float2* part  = (float2*)w;                       //   8 KB
    f16* Wqk  = (f16*)(w + 16384);                    //   1 MB   [1024,512]
    f16* Wv   = Wqk + (size_t)1024 * CC;              // 512 KB
    f16* Wp   = Wv  + (size_t)CC * CC;                // 512 KB
    float* qkb = (float*)(Wp + (size_t)CC * CC);      //   4 KB
    f16* xnT  = (f16*)((char*)qkb + 4096);            // 16 MB    [B][L,C]
    f16* QK   = xnT + (size_t)BB * LL * CC;           // 32 MB    [B][L,1024]
    f16* Vm   = QK  + (size_t)BB * LL * 1024;         // 16 MB    [B][C,L]
    f16* Pm   = Vm  + (size_t)BB * CC * LL;           // 64 MB    [B][L,L]
    float* rowpart = (float*)(Pm + (size_t)BB * LL * LL);  // 512 KB [B*L][8]
    f16* O2   = xnT;  // alias: xnT dead after gemm2
    size_t need = (size_t)((char*)(rowpart + (size_t)BB * LL * 8) - w);
    if (ws_size < need) {
        fill_marker<<<(out_size + 255) / 256, 256, 0, stream>>>(out, out_size);
        return;
    }

    convert_gn<<<dim3(1280), 256, 0, stream>>>(
        qw, kw, vw, pw, qb, kb, x, Wqk, Wv, Wp, qkb, part);
    gn_norm_t<<<dim3(LL / 64, CC / 64, BB), 256, 0, stream>>>(x, part, gw, gb, xnT);

    // GEMM1: [Q|K]t[l, n] = xnT[l,:] . Wqk[n,:] + qkb[n]     (M=L, N=1024, K=C)
    gemm_pipe<2, false, false, f16><<<dim3(1024 / 256, LL / 128, BB), 512, 0, stream>>>(
        xnT, (size_t)LL * CC, Wqk, 0, QK, (size_t)LL * 1024, qkb, nullptr,
        LL, CC, CC, CC, 1024, 1.0f);

    // GEMM2: V[c, l] = Wv[c,:] . xnT[l,:] + vb[c]            (M=C, N=L, K=C)
    gemm_bt<1, false, f16><<<dim3(LL / 128, CC / 128, BB), 256, 0, stream>>>(
        Wv, 0, xnT, (size_t)LL * CC, Vm, (size_t)CC * LL, nullptr, 0, vb,
        CC, LL, CC, CC, CC, LL, 1.0f);

    // GEMM3: P'[i, j] = exp(scale * Qt[i,:] . Kt[j,:]) ; rowpart  (M=L, N=L, K=C)
    gemm_pipe<0, true, false, f16><<<dim3(LL / 256, LL / 128, BB), 512, 0, stream>>>(
        QK, (size_t)LL * 1024, QK + CC, (size_t)LL * 1024, Pm, (size_t)LL * LL,
        nullptr, rowpart,
        LL, CC, 1024, 1024, LL, 0.04419417382415922f);

    // GEMM4: O2[i, c] = (P'[i,:] . V[c,:]) / rowsum[i]       (M=L, N=C, K=L)
    gemm_pipe<0, false, true, f16><<<dim3(CC / 256, LL / 128, BB), 512, 0, stream>>>(
        Pm, (size_t)LL * LL, Vm, (size_t)CC * LL, O2, (size_t)LL * CC,
        nullptr, rowpart,
        LL, LL, LL, LL, CC, 1.0f);

    // GEMM5: out[c, l] = Wp[c,:] . O2[l,:] + pb[c] + x[c,l]  (M=C, N=L, K=C)
    gemm_bt<1, true, float><<<dim3(LL / 128, CC / 128, BB), 256, 0, stream>>>(
        Wp, 0, O2, (size_t)LL * CC, out, (size_t)CC * LL, x, (size_t)CC * LL, pb,
        CC, LL, CC, CC, CC, LL, 1.0f);
}

// Round 14
// 169.701 us; speedup vs baseline: 1.0663x; 1.0663x over previous
//
#include <hip/hip_runtime.h>

#define BB 8
#define CC 512
#define LL 2048
#define GG 4
#define CPG 128   // channels per group

typedef _Float16 f16;
typedef _Float16 f16x4 __attribute__((ext_vector_type(4)));
typedef _Float16 f16x8 __attribute__((ext_vector_type(8)));
typedef float f32x4 __attribute__((ext_vector_type(4)));

__device__ __forceinline__ void gload_lds16(const f16* g, f16* l)
{
    __builtin_amdgcn_global_load_lds(
        (__attribute__((address_space(1))) void*)g,
        (__attribute__((address_space(3))) void*)l, 16, 0, 0);
}

// ---------------------------------------------------------------------------
// Fused setup kernel, grid 1410:
//   blocks    0-255 : Wv, Wp fp32 -> f16 (vectorized)
//   blocks  256-319 : transpose-convert qw -> WqT[a][o] f16
//   blocks  320-383 : transpose-convert kw -> WkT[b][o] f16
//   blocks  384-385 : c1[b] = sum_o kw[o][b] * qb[o]
//   blocks 386-1409 : GroupNorm partial sums (1024 = 32 slices x 4 g x 8 b)
// ---------------------------------------------------------------------------
__global__ __launch_bounds__(256) void convert_gn(
    const float* __restrict__ qw, const float* __restrict__ kw,
    const float* __restrict__ vw, const float* __restrict__ pw,
    const float* __restrict__ qb,
    const float* __restrict__ x,
    f16* __restrict__ WqT, f16* __restrict__ WkT,
    f16* __restrict__ Wv, f16* __restrict__ Wp,
    float* __restrict__ c1, float2* __restrict__ part)
{
    int bid = blockIdx.x;
    int tid = threadIdx.x;
    if (bid < 256) {
        int i = (bid * 256 + tid) * 4;
        float4 v4 = *(const float4*)(vw + i);
        float4 p4 = *(const float4*)(pw + i);
        f16x4 o;
        o[0] = (f16)v4.x; o[1] = (f16)v4.y; o[2] = (f16)v4.z; o[3] = (f16)v4.w;
        *(f16x4*)(Wv + i) = o;
        o[0] = (f16)p4.x; o[1] = (f16)p4.y; o[2] = (f16)p4.z; o[3] = (f16)p4.w;
        *(f16x4*)(Wp + i) = o;
    } else if (bid < 384) {
        // transpose 64x64 tile: src[o][a] fp32 -> dst[a][o] f16
        const float* src = (bid < 320) ? qw : kw;
        f16* dst = (bid < 320) ? WqT : WkT;
        int t = (bid - 256) & 63;
        int o0 = (t & 7) * 64, a0 = (t >> 3) * 64;
        __shared__ float ts[64][65];
        {
            int r = tid >> 2, c4 = (tid & 3) * 16;
#pragma unroll
            for (int e4 = 0; e4 < 4; ++e4) {
                float4 v = *(const float4*)(src + (size_t)(o0 + r) * CC + a0 + c4 + e4 * 4);
                ts[r][c4 + e4 * 4 + 0] = v.x; ts[r][c4 + e4 * 4 + 1] = v.y;
                ts[r][c4 + e4 * 4 + 2] = v.z; ts[r][c4 + e4 * 4 + 3] = v.w;
            }
        }
        __syncthreads();
        {
            int j8 = (tid & 7) * 8;
#pragma unroll
            for (int h = 0; h < 2; ++h) {
                int ai = (tid >> 3) + h * 32;
                f16x8 v;
#pragma unroll
                for (int e = 0; e < 8; ++e) v[e] = (f16)ts[j8 + e][ai];
                *(f16x8*)(dst + (size_t)(a0 + ai) * CC + o0 + j8) = v;
            }
        }
    } else if (bid < 386) {
        int b = (bid - 384) * 256 + tid;
        float s = 0.f;
        for (int o = 0; o < CC; ++o) s += kw[(size_t)o * CC + b] * qb[o];
        c1[b] = s;
    } else {
        int r = bid - 386;               // [0, 1024)
        int s = r & 31, g = (r >> 5) & 3, b = r >> 7;
        const float4* p = (const float4*)(x + (size_t)b * CC * LL
                                            + (size_t)g * CPG * LL + (size_t)s * 8192);
        float sum = 0.f, sq = 0.f;
        for (int i = tid; i < 2048; i += 256) {
            float4 v = p[i];
            sum += v.x + v.y + v.z + v.w;
            sq  += v.x * v.x + v.y * v.y + v.z * v.z + v.w * v.w;
        }
        for (int o = 32; o; o >>= 1) { sum += __shfl_xor(sum, o); sq += __shfl_xor(sq, o); }
        __shared__ float2 red[4];
        int wave = tid >> 6, lane = tid & 63;
        if (lane == 0) red[wave] = make_float2(sum, sq);
        __syncthreads();
        if (tid == 0) {
            float S = red[0].x + red[1].x + red[2].x + red[3].x;
            float Q = red[0].y + red[1].y + red[2].y + red[3].y;
            part[((size_t)b * GG + g) * 32 + s] = make_float2(S, Q);
        }
    }
}

// GroupNorm normalize + affine + TRANSPOSE: x [C,L] fp32 -> xnT [L,C] f16.
__global__ __launch_bounds__(256) void gn_norm_t(
    const float* __restrict__ x, const float2* __restrict__ part,
    const float* __restrict__ gw, const float* __restrict__ gb,
    f16* __restrict__ xnT)
{
    __shared__ float t[64][65];
    __shared__ float2 stLds;
    int l0 = blockIdx.x * 64, c0 = blockIdx.y * 64, b = blockIdx.z;
    int tid = threadIdx.x;
    if (tid < 32) {
        float2 p = part[((size_t)b * GG + (c0 >> 7)) * 32 + tid];
        float s = p.x, q = p.y;
        for (int o = 16; o; o >>= 1) { s += __shfl_xor(s, o); q += __shfl_xor(q, o); }
        if (tid == 0) {
            const float invN = 1.0f / (float)(CPG * LL);
            float mean = s * invN;
            float var  = q * invN - mean * mean;
            stLds = make_float2(mean, rsqrtf(var + 1e-6f));
        }
    }
    __syncthreads();
    float2 st = stLds;
    const float* xb = x + (size_t)b * CC * LL;
    {
        int c = tid >> 2, lb = (tid & 3) * 16;
        float g = gw[c0 + c], b2 = gb[c0 + c];
        const float4* src = (const float4*)(xb + (size_t)(c0 + c) * LL + l0 + lb);
#pragma unroll
        for (int q = 0; q < 4; ++q) {
            float4 v = src[q];
            int l = lb + q * 4;
            t[c][l + 0] = (v.x - st.x) * st.y * g + b2;
            t[c][l + 1] = (v.y - st.x) * st.y * g + b2;
            t[c][l + 2] = (v.z - st.x) * st.y * g + b2;
            t[c][l + 3] = (v.w - st.x) * st.y * g + b2;
        }
    }
    __syncthreads();
    f16* o = xnT + (size_t)b * LL * CC;
    {
        int c8 = (tid & 7) * 8;
#pragma unroll
        for (int h = 0; h < 2; ++h) {
            int l = (tid >> 3) + h * 32;
            f16x8 v;
#pragma unroll
            for (int u = 0; u < 8; ++u) v[u] = (f16)t[c8 + u][l];
            *(f16x8*)(o + (size_t)(l0 + l) * CC + c0 + c8) = v;
        }
    }
}

// ---------------------------------------------------------------------------
// Batched GEMM  C[M,N] = alpha * A[M,K] · B[N,K]^T (+bias)(+resid)
// R2-proven 2-barrier core. Tile 128 x (NBT*32), BK=64, 4 waves (2x2).
// Staging: global_load_lds w=16, linear LDS dest + inverse-swizzled source.
// Read swizzle: phys=(row*128+col)^((row&7)<<4), measured 0-conflict.
// XCD-aware bijective block swizzle (T1).
// Epilogue/extras:
//   BIAS_MODE 0/1(row)/2(col); RESID; ROWSCALE (v *= 1/rowsum via rowpart);
//   SOFTEXP: e = exp(min(acc*alpha + alpha*colb_in[col], 11)), f16 store +
//            deterministic per-block row sums -> rowpart;
//   ROWDOT:  colb_out[row] = sum_k c1[k]*A[row,k], accumulated in the K-loop
//            from the A fragments (softmax column-bias term).
// ---------------------------------------------------------------------------
template<int NBT, int BIAS_MODE, bool RESID, bool SOFTEXP, bool ROWSCALE,
         bool ROWDOT, typename OUT_T>
__global__ __launch_bounds__(256, 2) void gemm_bt(
    const f16* __restrict__ A, size_t sA,
    const f16* __restrict__ B, size_t sB,
    OUT_T* __restrict__ Co, size_t sC,
    const float* __restrict__ resid, size_t sR,
    const float* __restrict__ bias,
    float* __restrict__ rowpart,
    const float* __restrict__ c1d, float* __restrict__ colb_out,
    const float* __restrict__ colb_in,
    int M, int N, int K, int lda, int ldb, int ldc, float alpha)
{
    constexpr int BN = NBT * 32;

    const int tid  = threadIdx.x;
    const int lane = tid & 63;
    const int wave = tid >> 6;
    const int wr = wave >> 1, wc = wave & 1;
    const int l15 = lane & 15, lhi = lane >> 4;

    // XCD-aware bijective swizzle over the flattened grid (nwg % 8 == 0)
    const int GX = gridDim.x, GXY = gridDim.x * gridDim.y;
    const int nwg = GXY * gridDim.z;
    int lin = blockIdx.z * GXY + blockIdx.y * GX + blockIdx.x;
    int logical = (lin & 7) * (nwg >> 3) + (lin >> 3);
    const int bz = logical / GXY;
    int rem = logical - bz * GXY;
    const int bm = rem / GX;
    const int bn = rem - bm * GX;

    A  += (size_t)bz * sA;
    B  += (size_t)bz * sB;
    Co += (size_t)bz * sC;

    __shared__ f16 ldsA[128 * 64];
    __shared__ f16 ldsB[BN * 64];
    __shared__ float rsl[128];
    __shared__ float c1L[ROWDOT ? 512 : 1];
    __shared__ float cbL[SOFTEXP ? 256 : 1];

    f32x4 acc[4][NBT] = {};
    float rdot[4] = {0.f, 0.f, 0.f, 0.f};

    if constexpr (ROWSCALE) {
        if (tid < 128) {
            const float* rp = rowpart + ((size_t)bz * M + bm * 128 + tid) * 8;
            float s = 0.f;
#pragma unroll
            for (int k = 0; k < 8; ++k) s += rp[k];
            rsl[tid] = 1.0f / s;
        }
    }
    if constexpr (ROWDOT) {
        c1L[tid] = c1d[tid];
        c1L[tid + 256] = c1d[tid + 256];
    }
    if constexpr (SOFTEXP) {
        cbL[tid] = alpha * colb_in[(size_t)bz * N + bn * BN + tid];
    }
    // all LDS preloads ordered before use by the K-loop's first __syncthreads

    // staging source column (elements), inverse-swizzled; constant per lane
    const int srcColE = ((lane & 7) ^ (lane >> 3)) * 8;
    const int rowBase = wave * 8 + (lane >> 3);          // + it*32
    const f16* Ag = A + (size_t)(bm * 128 + rowBase) * lda + srcColE;
    const f16* Bg = B + (size_t)(bn * BN  + rowBase) * ldb + srcColE;

    for (int k0 = 0; k0 < K; k0 += 64) {
#pragma unroll
        for (int it = 0; it < 4; ++it)
            gload_lds16(Ag + (size_t)(it * 32) * lda + k0,
                        (f16*)((char*)ldsA + it * 4096 + wave * 1024));
#pragma unroll
        for (int it = 0; it < NBT; ++it)
            gload_lds16(Bg + (size_t)(it * 32) * ldb + k0,
                        (f16*)((char*)ldsB + it * 4096 + wave * 1024));
        __syncthreads();
#pragma unroll
        for (int kk = 0; kk < 64; kk += 32) {
            const int kb2 = (kk + lhi * 8) * 2;   // byte col of fragment
            f16x8 af[4], bfr[NBT];
#pragma unroll
            for (int m = 0; m < 4; ++m) {
                int row = wr * 64 + m * 16 + l15;
                int phys = ((row * 128 + kb2) ^ ((row & 7) << 4)) >> 1;
                af[m] = *(const f16x8*)(ldsA + phys);
            }
#pragma unroll
            for (int n = 0; n < NBT; ++n) {
                int row = wc * (NBT * 16) + n * 16 + l15;
                int phys = ((row * 128 + kb2) ^ ((row & 7) << 4)) >> 1;
                bfr[n] = *(const f16x8*)(ldsB + phys);
            }
            if constexpr (ROWDOT) {
                int kbase = k0 + kk + lhi * 8;
#pragma unroll
                for (int m = 0; m < 4; ++m)
#pragma unroll
                    for (int e = 0; e < 8; ++e)
                        rdot[m] += c1L[kbase + e] * (float)af[m][e];
            }
#pragma unroll
            for (int m = 0; m < 4; ++m)
#pragma unroll
                for (int n = 0; n < NBT; ++n)
                    acc[m][n] = __builtin_amdgcn_mfma_f32_16x16x32_f16(
                        af[m], bfr[n], acc[m][n], 0, 0, 0);
        }
        __syncthreads();
    }

    if constexpr (ROWDOT) {
#pragma unroll
        for (int m = 0; m < 4; ++m) {
            rdot[m] += __shfl_xor(rdot[m], 16);
            rdot[m] += __shfl_xor(rdot[m], 32);
        }
        if (wc == 0 && lhi == 0 && bn == 0) {
#pragma unroll
            for (int m = 0; m < 4; ++m)
                colb_out[(size_t)bz * M + bm * 128 + wr * 64 + m * 16 + l15] = rdot[m];
        }
    }

    if constexpr (SOFTEXP) {
        // exp epilogue + deterministic per-block row sums (no atomics)
        __shared__ float rs2[2][128];
        float rowacc[16];
#pragma unroll
        for (int i = 0; i < 16; ++i) rowacc[i] = 0.f;
#pragma unroll
        for (int m = 0; m < 4; ++m) {
#pragma unroll
            for (int n = 0; n < NBT; ++n) {
                int colL = wc * (NBT * 16) + n * 16 + l15;
                int col = bn * BN + colL;
#pragma unroll
                for (int r = 0; r < 4; ++r) {
                    int row = bm * 128 + wr * 64 + m * 16 + lhi * 4 + r;
                    float e = __expf(fminf(acc[m][n][r] * alpha + cbL[colL], 11.0f));
                    rowacc[m * 4 + r] += e;
                    Co[(size_t)row * ldc + col] = (OUT_T)e;
                }
            }
        }
#pragma unroll
        for (int off = 1; off < 16; off <<= 1)
#pragma unroll
            for (int i = 0; i < 16; ++i)
                rowacc[i] += __shfl_xor(rowacc[i], off);
        if (l15 == 0) {
#pragma unroll
            for (int i = 0; i < 16; ++i)
                rs2[wc][wr * 64 + (i >> 2) * 16 + lhi * 4 + (i & 3)] = rowacc[i];
        }
        __syncthreads();
        if (tid < 128) {
            int row = bm * 128 + tid;
            rowpart[((size_t)bz * M + row) * gridDim.x + bn] =
                rs2[0][tid] + rs2[1][tid];
        }
    } else {
#pragma unroll
        for (int m = 0; m < 4; ++m) {
#pragma unroll
            for (int n = 0; n < NBT; ++n) {
                int col = bn * BN + wc * (NBT * 16) + n * 16 + l15;
#pragma unroll
                for (int r = 0; r < 4; ++r) {
                    int row = bm * 128 + wr * 64 + m * 16 + lhi * 4 + r;
                    float v = acc[m][n][r] * alpha;
                    if (BIAS_MODE == 1) v += bias[row];
                    if (BIAS_MODE == 2) v += bias[col];
                    if (ROWSCALE) v *= rsl[row - bm * 128];
                    if (RESID) v += resid[(size_t)bz * sR + (size_t)row * ldc + col];
                    Co[(size_t)row * ldc + col] = (OUT_T)v;
                }
            }
        }
    }
}

// Fallback marker if workspace is too small
__global__ void fill_marker(float* out, int n)
{
    int i = blockIdx.x * 256 + threadIdx.x;
    if (i < n) out[i] = 12345.0f;
}

// ---------------------------------------------------------------------------
extern "C" void kernel_launch(void* const* d_in, const int* in_sizes, int n_in,
                              void* d_out, int out_size, void* d_ws, size_t ws_size,
                              hipStream_t stream)
{
    const float* x  = (const float*)d_in[0];
    const float* gw = (const float*)d_in[1];
    const float* gb = (const float*)d_in[2];
    const float* qw = (const float*)d_in[3];
    const float* qb = (const float*)d_in[4];
    const float* kw = (const float*)d_in[5];
    const float* kb = (const float*)d_in[6];  (void)kb; // cancels in softmax
    const float* vw = (const float*)d_in[7];
    const float* vb = (const float*)d_in[8];
    const float* pw = (const float*)d_in[9];
    const float* pb = (const float*)d_in[10];
    float* out = (float*)d_out;

    char* w = (char*)d_ws;
    float2* part = (float2*)w;                        //   8 KB
    f16* WqT  = (f16*)(w + 16384);                    // 512 KB  [a][o]
    f16* WkT  = WqT + (size_t)CC * CC;                // 512 KB  [b][o]
    f16* Wv   = WkT + (size_t)CC * CC;                // 512 KB
    f16* Wp   = Wv  + (size_t)CC * CC;                // 512 KB
    f16* Mf   = Wp  + (size_t)CC * CC;                // 512 KB  M=qw^T kw [a][b]
    float* c1 = (float*)(Mf + (size_t)CC * CC);       //   2 KB
    f16* xnT  = (f16*)((char*)c1 + 4096);             // 16 MB   [B][L,C]
    f16* ktT  = xnT + (size_t)BB * LL * CC;           // 16 MB   [B][L,C]
    f16* Vm   = ktT + (size_t)BB * LL * CC;           // 16 MB   [B][C,L]
    f16* Pm   = Vm  + (size_t)BB * CC * LL;           // 64 MB   [B][L,L]
    float* rowpart = (float*)(Pm + (size_t)BB * LL * LL);  // 512 KB [B*L][8]
    float* colb    = rowpart + (size_t)BB * LL * 8;        //  64 KB [B*L]
    f16* O2   = xnT;  // alias: xnT dead after GEMM3
    size_t need = (size_t)((char*)(colb + (size_t)BB * LL) - w);
    if (ws_size < need) {
        fill_marker<<<(out_size + 255) / 256, 256, 0, stream>>>(out, out_size);
        return;
    }

    convert_gn<<<dim3(1410), 256, 0, stream>>>(
        qw, kw, vw, pw, qb, x, WqT, WkT, Wv, Wp, c1, part);

    // M[a,b] = sum_o qw[o,a]*kw[o,b] = WqT . WkT^T   (512x512, 16 blocks)
    gemm_bt<4, 0, false, false, false, false, f16><<<dim3(4, 4, 1), 256, 0, stream>>>(
        WqT, 0, WkT, 0, Mf, 0, nullptr, 0, nullptr,
        nullptr, nullptr, nullptr, nullptr,
        CC, CC, CC, CC, CC, CC, 1.0f);

    gn_norm_t<<<dim3(LL / 64, CC / 64, BB), 256, 0, stream>>>(x, part, gw, gb, xnT);

    // ktT[l, a] = sum_b xnT[l,b]*M[a,b]; ROWDOT: colb[l] = sum_b c1[b]*xnT[l,b]
    gemm_bt<4, 0, false, false, false, true, f16><<<dim3(CC / 128, LL / 128, BB), 256, 0, stream>>>(
        xnT, (size_t)LL * CC, Mf, 0, ktT, (size_t)LL * CC, nullptr, 0, nullptr,
        nullptr, c1, colb, nullptr,
        LL, CC, CC, CC, CC, CC, 1.0f);

    // GEMM2: V[c, l] = Wv[c,:] . xnT[l,:] + vb[c]            (M=C, N=L, K=C)
    gemm_bt<4, 1, false, false, false, false, f16><<<dim3(LL / 128, CC / 128, BB), 256, 0, stream>>>(
        Wv, 0, xnT, (size_t)LL * CC, Vm, (size_t)CC * LL, nullptr, 0, vb,
        nullptr, nullptr, nullptr, nullptr,
        CC, LL, CC, CC, CC, LL, 1.0f);

    // GEMM3: P'[i,j] = exp(scale*(xnT_i . ktT_j + colb[j])) ; rowpart
    gemm_bt<8, 0, false, true, false, false, f16><<<dim3(LL / 256, LL / 128, BB), 256, 0, stream>>>(
        xnT, (size_t)LL * CC, ktT, (size_t)LL * CC, Pm, (size_t)LL * LL,
        nullptr, 0, nullptr,
        rowpart, nullptr, nullptr, colb,
        LL, LL, CC, CC, CC, LL, 0.04419417382415922f);

    // GEMM4: O2[i, c] = (P'[i,:] . V[c,:]) / rowsum[i]       (M=L, N=C, K=L)
    gemm_bt<4, 0, false, false, true, false, f16><<<dim3(CC / 128, LL / 128, BB), 256, 0, stream>>>(
        Pm, (size_t)LL * LL, Vm, (size_t)CC * LL, O2, (size_t)LL * CC,
        nullptr, 0, nullptr,
        rowpart, nullptr, nullptr, nullptr,
        LL, CC, LL, LL, LL, CC, 1.0f);

    // GEMM5: out[c, l] = Wp[c,:] . O2[l,:] + pb[c] + x[c,l]  (M=C, N=L, K=C)
    gemm_bt<4, 1, true, false, false, false, float><<<dim3(LL / 128, CC / 128, BB), 256, 0, stream>>>(
        Wp, 0, O2, (size_t)LL * CC, out, (size_t)CC * LL, x, (size_t)CC * LL, pb,
        nullptr, nullptr, nullptr, nullptr,
        CC, LL, CC, CC, CC, LL, 1.0f);
}

// Round 15
// 159.942 us; speedup vs baseline: 1.1313x; 1.0610x over previous
//
#include <hip/hip_runtime.h>

#define BB 8
#define CC 512
#define LL 2048
#define GG 4
#define CPG 128   // channels per group

typedef _Float16 f16;
typedef _Float16 f16x4 __attribute__((ext_vector_type(4)));
typedef _Float16 f16x8 __attribute__((ext_vector_type(8)));
typedef float f32x4 __attribute__((ext_vector_type(4)));

__device__ __forceinline__ void gload_lds16(const f16* g, f16* l)
{
    __builtin_amdgcn_global_load_lds(
        (__attribute__((address_space(1))) void*)g,
        (__attribute__((address_space(3))) void*)l, 16, 0, 0);
}

// ---------------------------------------------------------------------------
// Fused setup kernel, grid 1440:
//   blocks    0-255 : Wv, Wp fp32 -> f16 (vectorized)
//   blocks  256-319 : transpose-convert qw -> WqT[a][o] f16
//   blocks  320-383 : transpose-convert kw -> WkT[b][o] f16
//   blocks  384-415 : c1part[j][b] = sum_{o in [16j,16j+16)} kw[o][b]*qb[o]
//                     (32 coalesced partial blocks; R14's 2-block serial
//                      matvec was ~25 us latency-bound and gated the kernel)
//   blocks 416-1439 : GroupNorm partial sums (1024 = 32 slices x 4 g x 8 b)
// ---------------------------------------------------------------------------
__global__ __launch_bounds__(256) void convert_gn(
    const float* __restrict__ qw, const float* __restrict__ kw,
    const float* __restrict__ vw, const float* __restrict__ pw,
    const float* __restrict__ qb,
    const float* __restrict__ x,
    f16* __restrict__ WqT, f16* __restrict__ WkT,
    f16* __restrict__ Wv, f16* __restrict__ Wp,
    float* __restrict__ c1part, float2* __restrict__ part)
{
    int bid = blockIdx.x;
    int tid = threadIdx.x;
    if (bid < 256) {
        int i = (bid * 256 + tid) * 4;
        float4 v4 = *(const float4*)(vw + i);
        float4 p4 = *(const float4*)(pw + i);
        f16x4 o;
        o[0] = (f16)v4.x; o[1] = (f16)v4.y; o[2] = (f16)v4.z; o[3] = (f16)v4.w;
        *(f16x4*)(Wv + i) = o;
        o[0] = (f16)p4.x; o[1] = (f16)p4.y; o[2] = (f16)p4.z; o[3] = (f16)p4.w;
        *(f16x4*)(Wp + i) = o;
    } else if (bid < 384) {
        // transpose 64x64 tile: src[o][a] fp32 -> dst[a][o] f16
        const float* src = (bid < 320) ? qw : kw;
        f16* dst = (bid < 320) ? WqT : WkT;
        int t = (bid - 256) & 63;
        int o0 = (t & 7) * 64, a0 = (t >> 3) * 64;
        __shared__ float ts[64][65];
        {
            int r = tid >> 2, c4 = (tid & 3) * 16;
#pragma unroll
            for (int e4 = 0; e4 < 4; ++e4) {
                float4 v = *(const float4*)(src + (size_t)(o0 + r) * CC + a0 + c4 + e4 * 4);
                ts[r][c4 + e4 * 4 + 0] = v.x; ts[r][c4 + e4 * 4 + 1] = v.y;
                ts[r][c4 + e4 * 4 + 2] = v.z; ts[r][c4 + e4 * 4 + 3] = v.w;
            }
        }
        __syncthreads();
        {
            int j8 = (tid & 7) * 8;
#pragma unroll
            for (int h = 0; h < 2; ++h) {
                int ai = (tid >> 3) + h * 32;
                f16x8 v;
#pragma unroll
                for (int e = 0; e < 8; ++e) v[e] = (f16)ts[j8 + e][ai];
                *(f16x8*)(dst + (size_t)(a0 + ai) * CC + o0 + j8) = v;
            }
        }
    } else if (bid < 416) {
        int j = bid - 384;               // [0, 32)
        int o0 = j * 16;
        float s0 = 0.f, s1 = 0.f;
#pragma unroll
        for (int oo = 0; oo < 16; ++oo) {
            float qv = qb[o0 + oo];
            s0 += kw[(size_t)(o0 + oo) * CC + tid]       * qv;
            s1 += kw[(size_t)(o0 + oo) * CC + tid + 256] * qv;
        }
        c1part[j * CC + tid]       = s0;
        c1part[j * CC + tid + 256] = s1;
    } else {
        int r = bid - 416;               // [0, 1024)
        int s = r & 31, g = (r >> 5) & 3, b = r >> 7;
        const float4* p = (const float4*)(x + (size_t)b * CC * LL
                                            + (size_t)g * CPG * LL + (size_t)s * 8192);
        float sum = 0.f, sq = 0.f;
        for (int i = tid; i < 2048; i += 256) {
            float4 v = p[i];
            sum += v.x + v.y + v.z + v.w;
            sq  += v.x * v.x + v.y * v.y + v.z * v.z + v.w * v.w;
        }
        for (int o = 32; o; o >>= 1) { sum += __shfl_xor(sum, o); sq += __shfl_xor(sq, o); }
        __shared__ float2 red[4];
        int wave = tid >> 6, lane = tid & 63;
        if (lane == 0) red[wave] = make_float2(sum, sq);
        __syncthreads();
        if (tid == 0) {
            float S = red[0].x + red[1].x + red[2].x + red[3].x;
            float Q = red[0].y + red[1].y + red[2].y + red[3].y;
            part[((size_t)b * GG + g) * 32 + s] = make_float2(S, Q);
        }
    }
}

// GroupNorm normalize + affine + TRANSPOSE: x [C,L] fp32 -> xnT [L,C] f16.
__global__ __launch_bounds__(256) void gn_norm_t(
    const float* __restrict__ x, const float2* __restrict__ part,
    const float* __restrict__ gw, const float* __restrict__ gb,
    f16* __restrict__ xnT)
{
    __shared__ float t[64][65];
    __shared__ float2 stLds;
    int l0 = blockIdx.x * 64, c0 = blockIdx.y * 64, b = blockIdx.z;
    int tid = threadIdx.x;
    if (tid < 32) {
        float2 p = part[((size_t)b * GG + (c0 >> 7)) * 32 + tid];
        float s = p.x, q = p.y;
        for (int o = 16; o; o >>= 1) { s += __shfl_xor(s, o); q += __shfl_xor(q, o); }
        if (tid == 0) {
            const float invN = 1.0f / (float)(CPG * LL);
            float mean = s * invN;
            float var  = q * invN - mean * mean;
            stLds = make_float2(mean, rsqrtf(var + 1e-6f));
        }
    }
    __syncthreads();
    float2 st = stLds;
    const float* xb = x + (size_t)b * CC * LL;
    {
        int c = tid >> 2, lb = (tid & 3) * 16;
        float g = gw[c0 + c], b2 = gb[c0 + c];
        const float4* src = (const float4*)(xb + (size_t)(c0 + c) * LL + l0 + lb);
#pragma unroll
        for (int q = 0; q < 4; ++q) {
            float4 v = src[q];
            int l = lb + q * 4;
            t[c][l + 0] = (v.x - st.x) * st.y * g + b2;
            t[c][l + 1] = (v.y - st.x) * st.y * g + b2;
            t[c][l + 2] = (v.z - st.x) * st.y * g + b2;
            t[c][l + 3] = (v.w - st.x) * st.y * g + b2;
        }
    }
    __syncthreads();
    f16* o = xnT + (size_t)b * LL * CC;
    {
        int c8 = (tid & 7) * 8;
#pragma unroll
        for (int h = 0; h < 2; ++h) {
            int l = (tid >> 3) + h * 32;
            f16x8 v;
#pragma unroll
            for (int u = 0; u < 8; ++u) v[u] = (f16)t[c8 + u][l];
            *(f16x8*)(o + (size_t)(l0 + l) * CC + c0 + c8) = v;
        }
    }
}

// ---------------------------------------------------------------------------
// Batched GEMM  C[M,N] = alpha * A[M,K] · B[N,K]^T (+bias)(+resid)
// R2-proven 2-barrier core. Tile 128 x (NBT*32), BK=64, 4 waves (2x2).
// Staging: global_load_lds w=16, linear LDS dest + inverse-swizzled source.
// Read swizzle: phys=(row*128+col)^((row&7)<<4), measured 0-conflict.
// XCD-aware bijective block swizzle (T1).
// Epilogue/extras:
//   BIAS_MODE 0/1(row)/2(col); RESID; ROWSCALE (v *= 1/rowsum via rowpart);
//   SOFTEXP: e = exp(min(acc*alpha + alpha*colb_in[col], 11)), f16 store +
//            deterministic per-block row sums -> rowpart;
//   ROWDOT:  colb_out[row] = sum_k c1[k]*A[row,k]; c1 reduced from the 32
//            c1part slices at preload (fixed order, deterministic).
// ---------------------------------------------------------------------------
template<int NBT, int BIAS_MODE, bool RESID, bool SOFTEXP, bool ROWSCALE,
         bool ROWDOT, typename OUT_T>
__global__ __launch_bounds__(256, 2) void gemm_bt(
    const f16* __restrict__ A, size_t sA,
    const f16* __restrict__ B, size_t sB,
    OUT_T* __restrict__ Co, size_t sC,
    const float* __restrict__ resid, size_t sR,
    const float* __restrict__ bias,
    float* __restrict__ rowpart,
    const float* __restrict__ c1d, float* __restrict__ colb_out,
    const float* __restrict__ colb_in,
    int M, int N, int K, int lda, int ldb, int ldc, float alpha)
{
    constexpr int BN = NBT * 32;

    const int tid  = threadIdx.x;
    const int lane = tid & 63;
    const int wave = tid >> 6;
    const int wr = wave >> 1, wc = wave & 1;
    const int l15 = lane & 15, lhi = lane >> 4;

    // XCD-aware bijective swizzle over the flattened grid (nwg % 8 == 0)
    const int GX = gridDim.x, GXY = gridDim.x * gridDim.y;
    const int nwg = GXY * gridDim.z;
    int lin = blockIdx.z * GXY + blockIdx.y * GX + blockIdx.x;
    int logical = (lin & 7) * (nwg >> 3) + (lin >> 3);
    const int bz = logical / GXY;
    int rem = logical - bz * GXY;
    const int bm = rem / GX;
    const int bn = rem - bm * GX;

    A  += (size_t)bz * sA;
    B  += (size_t)bz * sB;
    Co += (size_t)bz * sC;

    __shared__ f16 ldsA[128 * 64];
    __shared__ f16 ldsB[BN * 64];
    __shared__ float rsl[128];
    __shared__ float c1L[ROWDOT ? 512 : 1];
    __shared__ float cbL[SOFTEXP ? 256 : 1];

    f32x4 acc[4][NBT] = {};
    float rdot[4] = {0.f, 0.f, 0.f, 0.f};

    if constexpr (ROWSCALE) {
        if (tid < 128) {
            const float* rp = rowpart + ((size_t)bz * M + bm * 128 + tid) * 8;
            float s = 0.f;
#pragma unroll
            for (int k = 0; k < 8; ++k) s += rp[k];
            rsl[tid] = 1.0f / s;
        }
    }
    if constexpr (ROWDOT) {
        float s0 = 0.f, s1 = 0.f;
#pragma unroll
        for (int j = 0; j < 32; ++j) {
            s0 += c1d[j * 512 + tid];
            s1 += c1d[j * 512 + tid + 256];
        }
        c1L[tid] = s0;
        c1L[tid + 256] = s1;
    }
    if constexpr (SOFTEXP) {
        cbL[tid] = alpha * colb_in[(size_t)bz * N + bn * BN + tid];
    }
    // all LDS preloads ordered before use by the K-loop's first __syncthreads

    // staging source column (elements), inverse-swizzled; constant per lane
    const int srcColE = ((lane & 7) ^ (lane >> 3)) * 8;
    const int rowBase = wave * 8 + (lane >> 3);          // + it*32
    const f16* Ag = A + (size_t)(bm * 128 + rowBase) * lda + srcColE;
    const f16* Bg = B + (size_t)(bn * BN  + rowBase) * ldb + srcColE;

    for (int k0 = 0; k0 < K; k0 += 64) {
#pragma unroll
        for (int it = 0; it < 4; ++it)
            gload_lds16(Ag + (size_t)(it * 32) * lda + k0,
                        (f16*)((char*)ldsA + it * 4096 + wave * 1024));
#pragma unroll
        for (int it = 0; it < NBT; ++it)
            gload_lds16(Bg + (size_t)(it * 32) * ldb + k0,
                        (f16*)((char*)ldsB + it * 4096 + wave * 1024));
        __syncthreads();
#pragma unroll
        for (int kk = 0; kk < 64; kk += 32) {
            const int kb2 = (kk + lhi * 8) * 2;   // byte col of fragment
            f16x8 af[4], bfr[NBT];
#pragma unroll
            for (int m = 0; m < 4; ++m) {
                int row = wr * 64 + m * 16 + l15;
                int phys = ((row * 128 + kb2) ^ ((row & 7) << 4)) >> 1;
                af[m] = *(const f16x8*)(ldsA + phys);
            }
#pragma unroll
            for (int n = 0; n < NBT; ++n) {
                int row = wc * (NBT * 16) + n * 16 + l15;
                int phys = ((row * 128 + kb2) ^ ((row & 7) << 4)) >> 1;
                bfr[n] = *(const f16x8*)(ldsB + phys);
            }
            if constexpr (ROWDOT) {
                int kbase = k0 + kk + lhi * 8;
#pragma unroll
                for (int m = 0; m < 4; ++m)
#pragma unroll
                    for (int e = 0; e < 8; ++e)
                        rdot[m] += c1L[kbase + e] * (float)af[m][e];
            }
#pragma unroll
            for (int m = 0; m < 4; ++m)
#pragma unroll
                for (int n = 0; n < NBT; ++n)
                    acc[m][n] = __builtin_amdgcn_mfma_f32_16x16x32_f16(
                        af[m], bfr[n], acc[m][n], 0, 0, 0);
        }
        __syncthreads();
    }

    if constexpr (ROWDOT) {
#pragma unroll
        for (int m = 0; m < 4; ++m) {
            rdot[m] += __shfl_xor(rdot[m], 16);
            rdot[m] += __shfl_xor(rdot[m], 32);
        }
        if (wc == 0 && lhi == 0 && bn == 0) {
#pragma unroll
            for (int m = 0; m < 4; ++m)
                colb_out[(size_t)bz * M + bm * 128 + wr * 64 + m * 16 + l15] = rdot[m];
        }
    }

    if constexpr (SOFTEXP) {
        // exp epilogue + deterministic per-block row sums (no atomics)
        __shared__ float rs2[2][128];
        float rowacc[16];
#pragma unroll
        for (int i = 0; i < 16; ++i) rowacc[i] = 0.f;
#pragma unroll
        for (int m = 0; m < 4; ++m) {
#pragma unroll
            for (int n = 0; n < NBT; ++n) {
                int colL = wc * (NBT * 16) + n * 16 + l15;
                int col = bn * BN + colL;
#pragma unroll
                for (int r = 0; r < 4; ++r) {
                    int row = bm * 128 + wr * 64 + m * 16 + lhi * 4 + r;
                    float e = __expf(fminf(acc[m][n][r] * alpha + cbL[colL], 11.0f));
                    rowacc[m * 4 + r] += e;
                    Co[(size_t)row * ldc + col] = (OUT_T)e;
                }
            }
        }
#pragma unroll
        for (int off = 1; off < 16; off <<= 1)
#pragma unroll
            for (int i = 0; i < 16; ++i)
                rowacc[i] += __shfl_xor(rowacc[i], off);
        if (l15 == 0) {
#pragma unroll
            for (int i = 0; i < 16; ++i)
                rs2[wc][wr * 64 + (i >> 2) * 16 + lhi * 4 + (i & 3)] = rowacc[i];
        }
        __syncthreads();
        if (tid < 128) {
            int row = bm * 128 + tid;
            rowpart[((size_t)bz * M + row) * gridDim.x + bn] =
                rs2[0][tid] + rs2[1][tid];
        }
    } else {
#pragma unroll
        for (int m = 0; m < 4; ++m) {
#pragma unroll
            for (int n = 0; n < NBT; ++n) {
                int col = bn * BN + wc * (NBT * 16) + n * 16 + l15;
#pragma unroll
                for (int r = 0; r < 4; ++r) {
                    int row = bm * 128 + wr * 64 + m * 16 + lhi * 4 + r;
                    float v = acc[m][n][r] * alpha;
                    if (BIAS_MODE == 1) v += bias[row];
                    if (BIAS_MODE == 2) v += bias[col];
                    if (ROWSCALE) v *= rsl[row - bm * 128];
                    if (RESID) v += resid[(size_t)bz * sR + (size_t)row * ldc + col];
                    Co[(size_t)row * ldc + col] = (OUT_T)v;
                }
            }
        }
    }
}

// Fallback marker if workspace is too small
__global__ void fill_marker(float* out, int n)
{
    int i = blockIdx.x * 256 + threadIdx.x;
    if (i < n) out[i] = 12345.0f;
}

// ---------------------------------------------------------------------------
extern "C" void kernel_launch(void* const* d_in, const int* in_sizes, int n_in,
                              void* d_out, int out_size, void* d_ws, size_t ws_size,
                              hipStream_t stream)
{
    const float* x  = (const float*)d_in[0];
    const float* gw = (const float*)d_in[1];
    const float* gb = (const float*)d_in[2];
    const float* qw = (const float*)d_in[3];
    const float* qb = (const float*)d_in[4];
    const float* kw = (const float*)d_in[5];
    const float* kb = (const float*)d_in[6];  (void)kb; // cancels in softmax
    const float* vw = (const float*)d_in[7];
    const float* vb = (const float*)d_in[8];
    const float* pw = (const float*)d_in[9];
    const float* pb = (const float*)d_in[10];
    float* out = (float*)d_out;

    char* w = (char*)d_ws;
    float2* part = (float2*)w;                        //   8 KB
    f16* WqT  = (f16*)(w + 16384);                    // 512 KB  [a][o]
    f16* WkT  = WqT + (size_t)CC * CC;                // 512 KB  [b][o]
    f16* Wv   = WkT + (size_t)CC * CC;                // 512 KB
    f16* Wp   = Wv  + (size_t)CC * CC;                // 512 KB
    f16* Mf   = Wp  + (size_t)CC * CC;                // 512 KB  M=qw^T kw [a][b]
    float* c1part = (float*)(Mf + (size_t)CC * CC);   //  64 KB  [32][512]
    f16* xnT  = (f16*)((char*)c1part + 65536);        // 16 MB   [B][L,C]
    f16* ktT  = xnT + (size_t)BB * LL * CC;           // 16 MB   [B][L,C]
    f16* Vm   = ktT + (size_t)BB * LL * CC;           // 16 MB   [B][C,L]
    f16* Pm   = Vm  + (size_t)BB * CC * LL;           // 64 MB   [B][L,L]
    float* rowpart = (float*)(Pm + (size_t)BB * LL * LL);  // 512 KB [B*L][8]
    float* colb    = rowpart + (size_t)BB * LL * 8;        //  64 KB [B*L]
    f16* O2   = xnT;  // alias: xnT dead after GEMM3
    size_t need = (size_t)((char*)(colb + (size_t)BB * LL) - w);
    if (ws_size < need) {
        fill_marker<<<(out_size + 255) / 256, 256, 0, stream>>>(out, out_size);
        return;
    }

    convert_gn<<<dim3(1440), 256, 0, stream>>>(
        qw, kw, vw, pw, qb, x, WqT, WkT, Wv, Wp, c1part, part);

    // M[a,b] = sum_o qw[o,a]*kw[o,b] = WqT . WkT^T   (512x512, 16 blocks)
    gemm_bt<4, 0, false, false, false, false, f16><<<dim3(4, 4, 1), 256, 0, stream>>>(
        WqT, 0, WkT, 0, Mf, 0, nullptr, 0, nullptr,
        nullptr, nullptr, nullptr, nullptr,
        CC, CC, CC, CC, CC, CC, 1.0f);

    gn_norm_t<<<dim3(LL / 64, CC / 64, BB), 256, 0, stream>>>(x, part, gw, gb, xnT);

    // ktT[l, a] = sum_b xnT[l,b]*M[a,b]; ROWDOT: colb[l] = sum_b c1[b]*xnT[l,b]
    gemm_bt<4, 0, false, false, false, true, f16><<<dim3(CC / 128, LL / 128, BB), 256, 0, stream>>>(
        xnT, (size_t)LL * CC, Mf, 0, ktT, (size_t)LL * CC, nullptr, 0, nullptr,
        nullptr, c1part, colb, nullptr,
        LL, CC, CC, CC, CC, CC, 1.0f);

    // GEMM2: V[c, l] = Wv[c,:] . xnT[l,:] + vb[c]            (M=C, N=L, K=C)
    gemm_bt<4, 1, false, false, false, false, f16><<<dim3(LL / 128, CC / 128, BB), 256, 0, stream>>>(
        Wv, 0, xnT, (size_t)LL * CC, Vm, (size_t)CC * LL, nullptr, 0, vb,
        nullptr, nullptr, nullptr, nullptr,
        CC, LL, CC, CC, CC, LL, 1.0f);

    // GEMM3: P'[i,j] = exp(scale*(xnT_i . ktT_j + colb[j])) ; rowpart
    gemm_bt<8, 0, false, true, false, false, f16><<<dim3(LL / 256, LL / 128, BB), 256, 0, stream>>>(
        xnT, (size_t)LL * CC, ktT, (size_t)LL * CC, Pm, (size_t)LL * LL,
        nullptr, 0, nullptr,
        rowpart, nullptr, nullptr, colb,
        LL, LL, CC, CC, CC, LL, 0.04419417382415922f);

    // GEMM4: O2[i, c] = (P'[i,:] . V[c,:]) / rowsum[i]       (M=L, N=C, K=L)
    gemm_bt<4, 0, false, false, true, false, f16><<<dim3(CC / 128, LL / 128, BB), 256, 0, stream>>>(
        Pm, (size_t)LL * LL, Vm, (size_t)CC * LL, O2, (size_t)LL * CC,
        nullptr, 0, nullptr,
        rowpart, nullptr, nullptr, nullptr,
        LL, CC, LL, LL, LL, CC, 1.0f);

    // GEMM5: out[c, l] = Wp[c,:] . O2[l,:] + pb[c] + x[c,l]  (M=C, N=L, K=C)
    gemm_bt<4, 1, true, false, false, false, float><<<dim3(LL / 128, CC / 128, BB), 256, 0, stream>>>(
        Wp, 0, O2, (size_t)LL * CC, out, (size_t)CC * LL, x, (size_t)CC * LL, pb,
        nullptr, nullptr, nullptr, nullptr,
        CC, LL, CC, CC, CC, LL, 1.0f);
}

// Round 16
// 152.932 us; speedup vs baseline: 1.1832x; 1.0458x over previous
//
#include <hip/hip_runtime.h>

#define BB 8
#define CC 512
#define LL 2048
#define GG 4
#define CPG 128   // channels per group

typedef _Float16 f16;
typedef _Float16 f16x4 __attribute__((ext_vector_type(4)));
typedef _Float16 f16x8 __attribute__((ext_vector_type(8)));
typedef float f32x4 __attribute__((ext_vector_type(4)));

__device__ __forceinline__ void gload_lds16(const f16* g, f16* l)
{
    __builtin_amdgcn_global_load_lds(
        (__attribute__((address_space(1))) void*)g,
        (__attribute__((address_space(3))) void*)l, 16, 0, 0);
}

// ---------------------------------------------------------------------------
// Fused: weight conversion, vectorized float4->f16x4 (blocks 0-255)
//        + GroupNorm partial sums (blocks 256-1279)
// ---------------------------------------------------------------------------
__global__ __launch_bounds__(256) void convert_gn(
    const float* __restrict__ qw, const float* __restrict__ kw,
    const float* __restrict__ vw, const float* __restrict__ pw,
    const float* __restrict__ qb, const float* __restrict__ kb,
    const float* __restrict__ x,
    f16* __restrict__ Wqk, f16* __restrict__ Wv, f16* __restrict__ Wp,
    float* __restrict__ qkb, float2* __restrict__ part)
{
    int bid = blockIdx.x;
    if (bid < 256) {
        int j = bid * 256 + threadIdx.x;
        int i = j * 4;                       // covers CC*CC exactly
        float4 q4 = *(const float4*)(qw + i);
        float4 k4 = *(const float4*)(kw + i);
        float4 v4 = *(const float4*)(vw + i);
        float4 p4 = *(const float4*)(pw + i);
        f16x4 o;
        o[0] = (f16)q4.x; o[1] = (f16)q4.y; o[2] = (f16)q4.z; o[3] = (f16)q4.w;
        *(f16x4*)(Wqk + i) = o;
        o[0] = (f16)k4.x; o[1] = (f16)k4.y; o[2] = (f16)k4.z; o[3] = (f16)k4.w;
        *(f16x4*)(Wqk + CC * CC + i) = o;
        o[0] = (f16)v4.x; o[1] = (f16)v4.y; o[2] = (f16)v4.z; o[3] = (f16)v4.w;
        *(f16x4*)(Wv + i) = o;
        o[0] = (f16)p4.x; o[1] = (f16)p4.y; o[2] = (f16)p4.z; o[3] = (f16)p4.w;
        *(f16x4*)(Wp + i) = o;
        if (j < CC) { qkb[j] = qb[j]; qkb[CC + j] = kb[j]; }
    } else {
        int r = bid - 256;
        int s = r & 31, g = (r >> 5) & 3, b = r >> 7;
        const float4* p = (const float4*)(x + (size_t)b * CC * LL
                                            + (size_t)g * CPG * LL + (size_t)s * 8192);
        float sum = 0.f, sq = 0.f;
        for (int i = threadIdx.x; i < 2048; i += 256) {
            float4 v = p[i];
            sum += v.x + v.y + v.z + v.w;
            sq  += v.x * v.x + v.y * v.y + v.z * v.z + v.w * v.w;
        }
        for (int o = 32; o; o >>= 1) { sum += __shfl_xor(sum, o); sq += __shfl_xor(sq, o); }
        __shared__ float2 red[4];
        int wave = threadIdx.x >> 6, lane = threadIdx.x & 63;
        if (lane == 0) red[wave] = make_float2(sum, sq);
        __syncthreads();
        if (threadIdx.x == 0) {
            float S = red[0].x + red[1].x + red[2].x + red[3].x;
            float Q = red[0].y + red[1].y + red[2].y + red[3].y;
            part[((size_t)b * GG + g) * 32 + s] = make_float2(S, Q);
        }
    }
}

// GroupNorm normalize + affine + TRANSPOSE: x [C,L] fp32 -> xnT [L,C] f16.
// Stats derived in-block from the 32 per-slice partials. Vectorized paths:
// x read float4 x4 (16B/lane), xnT write f16x8 (16B/lane, 8-row x 64-col
// coalesced wave segments); LDS re-read is 2-way bank-aliased (free, m136).
__global__ __launch_bounds__(256) void gn_norm_t(
    const float* __restrict__ x, const float2* __restrict__ part,
    const float* __restrict__ gw, const float* __restrict__ gb,
    f16* __restrict__ xnT)
{
    __shared__ float t[64][65];
    __shared__ float2 stLds;
    int l0 = blockIdx.x * 64, c0 = blockIdx.y * 64, b = blockIdx.z;
    int tid = threadIdx.x;
    if (tid < 32) {
        float2 p = part[((size_t)b * GG + (c0 >> 7)) * 32 + tid];
        float s = p.x, q = p.y;
        for (int o = 16; o; o >>= 1) { s += __shfl_xor(s, o); q += __shfl_xor(q, o); }
        if (tid == 0) {
            const float invN = 1.0f / (float)(CPG * LL);
            float mean = s * invN;
            float var  = q * invN - mean * mean;
            stLds = make_float2(mean, rsqrtf(var + 1e-6f));
        }
    }
    __syncthreads();
    float2 st = stLds;
    const float* xb = x + (size_t)b * CC * LL;
    {
        int c = tid >> 2, lb = (tid & 3) * 16;
        float g = gw[c0 + c], b2 = gb[c0 + c];
        const float4* src = (const float4*)(xb + (size_t)(c0 + c) * LL + l0 + lb);
#pragma unroll
        for (int q = 0; q < 4; ++q) {
            float4 v = src[q];
            int l = lb + q * 4;
            t[c][l + 0] = (v.x - st.x) * st.y * g + b2;
            t[c][l + 1] = (v.y - st.x) * st.y * g + b2;
            t[c][l + 2] = (v.z - st.x) * st.y * g + b2;
            t[c][l + 3] = (v.w - st.x) * st.y * g + b2;
        }
    }
    __syncthreads();
    f16* o = xnT + (size_t)b * LL * CC;
    {
        int c8 = (tid & 7) * 8;
#pragma unroll
        for (int h = 0; h < 2; ++h) {
            int l = (tid >> 3) + h * 32;
            f16x8 v;
#pragma unroll
            for (int u = 0; u < 8; ++u) v[u] = (f16)t[c8 + u][l];
            *(f16x8*)(o + (size_t)(l0 + l) * CC + c0 + c8) = v;
        }
    }
}

// ---------------------------------------------------------------------------
// Batched GEMM  C[M,N] = alpha * A[M,K] · B[N,K]^T (+bias)(+resid)
// Tile 128 x (NBT*32), BK=64, 4 waves (2x2), per-wave 64 x (NBT*16).
//   NBT=4: 128x128, 33.5KB LDS;  NBT=8: 128x256, 50KB LDS.
// __launch_bounds__(256,2) — R10 lesson: forcing >=3 blocks/CU caps VGPR
// below the accumulator footprint and spills acc to scratch (WRITE_SIZE 5x).
// Staging: global_load_lds w=16, linear LDS dest + inverse-swizzled source.
// Read swizzle: phys=(row*128+col)^((row&7)<<4), measured 0-conflict.
// XCD-aware bijective block swizzle (T1): logical = (hw&7)*(nwg/8) + hw>>3.
// Epilogue modes: BIAS_MODE 0/1(row)/2(col); RESID; SOFTEXP (exp + per-block
// row sums -> rowpart[(bz*M+row)*gridDim.x + bn]); ROWSCALE (reads the 8
// rowparts per row in a prologue, v *= 1/sum).
// ---------------------------------------------------------------------------
template<int NBT, int BIAS_MODE, bool RESID, bool SOFTEXP, bool ROWSCALE, typename OUT_T>
__global__ __launch_bounds__(256, 2) void gemm_bt(
    const f16* __restrict__ A, size_t sA,
    const f16* __restrict__ B, size_t sB,
    OUT_T* __restrict__ Co, size_t sC,
    const float* __restrict__ resid, size_t sR,
    const float* __restrict__ bias,
    float* __restrict__ rowpart,
    int M, int N, int K, int lda, int ldb, int ldc, float alpha)
{
    constexpr int BN = NBT * 32;

    const int tid  = threadIdx.x;
    const int lane = tid & 63;
    const int wave = tid >> 6;
    const int wr = wave >> 1, wc = wave & 1;
    const int l15 = lane & 15, lhi = lane >> 4;

    // XCD-aware bijective swizzle over the flattened grid (nwg % 8 == 0)
    const int GX = gridDim.x, GXY = gridDim.x * gridDim.y;
    const int nwg = GXY * gridDim.z;
    int lin = blockIdx.z * GXY + blockIdx.y * GX + blockIdx.x;
    int logical = (lin & 7) * (nwg >> 3) + (lin >> 3);
    const int bz = logical / GXY;
    int rem = logical - bz * GXY;
    const int bm = rem / GX;
    const int bn = rem - bm * GX;

    A  += (size_t)bz * sA;
    B  += (size_t)bz * sB;
    Co += (size_t)bz * sC;

    __shared__ f16 ldsA[128 * 64];
    __shared__ f16 ldsB[BN * 64];
    __shared__ float rsl[128];

    f32x4 acc[4][NBT] = {};

    if constexpr (ROWSCALE) {
        if (tid < 128) {
            const float* rp = rowpart + ((size_t)bz * M + bm * 128 + tid) * 8;
            float s = 0.f;
#pragma unroll
            for (int k = 0; k < 8; ++k) s += rp[k];
            rsl[tid] = 1.0f / s;
        }
        // first __syncthreads inside the K-loop orders rsl before epilogue use
    }

    // staging source column (elements), inverse-swizzled; constant per lane
    const int srcColE = ((lane & 7) ^ (lane >> 3)) * 8;
    const int rowBase = wave * 8 + (lane >> 3);          // + it*32
    const f16* Ag = A + (size_t)(bm * 128 + rowBase) * lda + srcColE;
    const f16* Bg = B + (size_t)(bn * BN  + rowBase) * ldb + srcColE;

    for (int k0 = 0; k0 < K; k0 += 64) {
#pragma unroll
        for (int it = 0; it < 4; ++it)
            gload_lds16(Ag + (size_t)(it * 32) * lda + k0,
                        (f16*)((char*)ldsA + it * 4096 + wave * 1024));
#pragma unroll
        for (int it = 0; it < NBT; ++it)
            gload_lds16(Bg + (size_t)(it * 32) * ldb + k0,
                        (f16*)((char*)ldsB + it * 4096 + wave * 1024));
        __syncthreads();
#pragma unroll
        for (int kk = 0; kk < 64; kk += 32) {
            const int kb2 = (kk + lhi * 8) * 2;   // byte col of fragment
            f16x8 af[4], bfr[NBT];
#pragma unroll
            for (int m = 0; m < 4; ++m) {
                int row = wr * 64 + m * 16 + l15;
                int phys = ((row * 128 + kb2) ^ ((row & 7) << 4)) >> 1;
                af[m] = *(const f16x8*)(ldsA + phys);
            }
#pragma unroll
            for (int n = 0; n < NBT; ++n) {
                int row = wc * (NBT * 16) + n * 16 + l15;
                int phys = ((row * 128 + kb2) ^ ((row & 7) << 4)) >> 1;
                bfr[n] = *(const f16x8*)(ldsB + phys);
            }
#pragma unroll
            for (int m = 0; m < 4; ++m)
#pragma unroll
                for (int n = 0; n < NBT; ++n)
                    acc[m][n] = __builtin_amdgcn_mfma_f32_16x16x32_f16(
                        af[m], bfr[n], acc[m][n], 0, 0, 0);
        }
        __syncthreads();
    }

    if constexpr (SOFTEXP) {
        // exp epilogue + deterministic per-block row sums (no atomics)
        __shared__ float rs2[2][128];
        float rowacc[16];
#pragma unroll
        for (int i = 0; i < 16; ++i) rowacc[i] = 0.f;
#pragma unroll
        for (int m = 0; m < 4; ++m) {
#pragma unroll
            for (int n = 0; n < NBT; ++n) {
                int col = bn * BN + wc * (NBT * 16) + n * 16 + l15;
#pragma unroll
                for (int r = 0; r < 4; ++r) {
                    int row = bm * 128 + wr * 64 + m * 16 + lhi * 4 + r;
                    float e = __expf(fminf(acc[m][n][r] * alpha, 11.0f));
                    rowacc[m * 4 + r] += e;
                    Co[(size_t)row * ldc + col] = (OUT_T)e;
                }
            }
        }
        // butterfly over l15 group (lanes sharing lhi hold the same rows)
#pragma unroll
        for (int off = 1; off < 16; off <<= 1)
#pragma unroll
            for (int i = 0; i < 16; ++i)
                rowacc[i] += __shfl_xor(rowacc[i], off);
        if (l15 == 0) {
#pragma unroll
            for (int i = 0; i < 16; ++i)
                rs2[wc][wr * 64 + (i >> 2) * 16 + lhi * 4 + (i & 3)] = rowacc[i];
        }
        __syncthreads();
        if (tid < 128) {
            int row = bm * 128 + tid;
            rowpart[((size_t)bz * M + row) * gridDim.x + bn] =
                rs2[0][tid] + rs2[1][tid];
        }
    } else {
#pragma unroll
        for (int m = 0; m < 4; ++m) {
#pragma unroll
            for (int n = 0; n < NBT; ++n) {
                int col = bn * BN + wc * (NBT * 16) + n * 16 + l15;
#pragma unroll
                for (int r = 0; r < 4; ++r) {
                    int row = bm * 128 + wr * 64 + m * 16 + lhi * 4 + r;
                    float v = acc[m][n][r] * alpha;
                    if (BIAS_MODE == 1) v += bias[row];
                    if (BIAS_MODE == 2) v += bias[col];
                    if (ROWSCALE) v *= rsl[row - bm * 128];
                    if (RESID) v += resid[(size_t)bz * sR + (size_t)row * ldc + col];
                    Co[(size_t)row * ldc + col] = (OUT_T)v;
                }
            }
        }
    }
}

// Fallback marker if workspace is too small (distinct absmax signal ~12345)
__global__ void fill_marker(float* out, int n)
{
    int i = blockIdx.x * 256 + threadIdx.x;
    if (i < n) out[i] = 12345.0f;
}

// ---------------------------------------------------------------------------
extern "C" void kernel_launch(void* const* d_in, const int* in_sizes, int n_in,
                              void* d_out, int out_size, void* d_ws, size_t ws_size,
                              hipStream_t stream)
{
    const float* x  = (const float*)d_in[0];
    const float* gw = (const float*)d_in[1];
    const float* gb = (const float*)d_in[2];
    const float* qw = (const float*)d_in[3];
    const float* qb = (const float*)d_in[4];
    const float* kw = (const float*)d_in[5];
    const float* kb = (const float*)d_in[6];
    const float* vw = (const float*)d_in[7];
    const float* vb = (const float*)d_in[8];
    const float* pw = (const float*)d_in[9];
    const float* pb = (const float*)d_in[10];
    float* out = (float*)d_out;

    // workspace layout (bytes)
    char* w = (char*)d_ws;
    float2* part  = (float2*)w;                       //   8 KB
    f16* Wqk  = (f16*)(w + 16384);                    //   1 MB   [1024,512]
    f16* Wv   = Wqk + (size_t)1024 * CC;              // 512 KB   [512,512]
    f16* Wp   = Wv  + (size_t)CC * CC;                // 512 KB
    float* qkb = (float*)(Wp + (size_t)CC * CC);      //   4 KB
    f16* xnT  = (f16*)((char*)qkb + 4096);            // 16 MB    [B][L,C]
    f16* QK   = xnT + (size_t)BB * LL * CC;           // 32 MB    [B][L,1024]
    f16* Vm   = QK  + (size_t)BB * LL * 1024;         // 16 MB    [B][C,L]
    f16* Pm   = Vm  + (size_t)BB * CC * LL;           // 64 MB    [B][L,L]
    float* rowpart = (float*)(Pm + (size_t)BB * LL * LL);  // 512 KB [B*L][8]
    f16* O2   = xnT;  // alias: xnT dead after gemm2  //          [B][L,C]
    size_t need = (size_t)((char*)(rowpart + (size_t)BB * LL * 8) - w);
    if (ws_size < need) {
        fill_marker<<<(out_size + 255) / 256, 256, 0, stream>>>(out, out_size);
        return;
    }

    convert_gn<<<dim3(1280), 256, 0, stream>>>(
        qw, kw, vw, pw, qb, kb, x, Wqk, Wv, Wp, qkb, part);
    gn_norm_t<<<dim3(LL / 64, CC / 64, BB), 256, 0, stream>>>(x, part, gw, gb, xnT);

    // GEMM1: [Q|K]t[l, n] = xnT[l,:] . Wqk[n,:] + qkb[n]     (M=L, N=1024, K=C)
    gemm_bt<8, 2, false, false, false, f16><<<dim3(1024 / 256, LL / 128, BB), 256, 0, stream>>>(
        xnT, (size_t)LL * CC, Wqk, 0, QK, (size_t)LL * 1024, nullptr, 0, qkb,
        nullptr,
        LL, 1024, CC, CC, CC, 1024, 1.0f);

    // GEMM2: V[c, l] = Wv[c,:] . xnT[l,:] + vb[c]            (M=C, N=L, K=C)
    gemm_bt<4, 1, false, false, false, f16><<<dim3(LL / 128, CC / 128, BB), 256, 0, stream>>>(
        Wv, 0, xnT, (size_t)LL * CC, Vm, (size_t)CC * LL, nullptr, 0, vb,
        nullptr,
        CC, LL, CC, CC, CC, LL, 1.0f);

    // GEMM3: P'[i, j] = exp(scale * Qt[i,:] . Kt[j,:]) ; rowpart  (M=L, N=L, K=C)
    gemm_bt<8, 0, false, true, false, f16><<<dim3(LL / 256, LL / 128, BB), 256, 0, stream>>>(
        QK, (size_t)LL * 1024, QK + CC, (size_t)LL * 1024, Pm, (size_t)LL * LL,
        nullptr, 0, nullptr,
        rowpart,
        LL, LL, CC, 1024, 1024, LL, 0.04419417382415922f);

    // GEMM4: O2[i, c] = (P'[i,:] . V[c,:]) / rowsum[i]       (M=L, N=C, K=L)
    gemm_bt<4, 0, false, false, true, f16><<<dim3(CC / 128, LL / 128, BB), 256, 0, stream>>>(
        Pm, (size_t)LL * LL, Vm, (size_t)CC * LL, O2, (size_t)LL * CC,
        nullptr, 0, nullptr,
        rowpart,
        LL, CC, LL, LL, LL, CC, 1.0f);

    // GEMM5: out[c, l] = Wp[c,:] . O2[l,:] + pb[c] + x[c,l]  (M=C, N=L, K=C)
    gemm_bt<4, 1, true, false, false, float><<<dim3(LL / 128, CC / 128, BB), 256, 0, stream>>>(
        Wp, 0, O2, (size_t)LL * CC, out, (size_t)CC * LL, x, (size_t)CC * LL, pb,
        nullptr,
        CC, LL, CC, CC, CC, LL, 1.0f);
}